// Round 1
// baseline (495.498 us; speedup 1.0000x reference)
//
#include <hip/hip_runtime.h>
#include <math.h>

#define KHALF 5

// K1: effective conv->proj weights: w_eff[k*D+d] = sum_c conv_w[k,d,c]*proj_w[c]
__global__ void k_weff(const float* __restrict__ conv_w, const float* __restrict__ conv_b,
                       const float* __restrict__ proj_w, const float* __restrict__ proj_b,
                       float* __restrict__ w_eff, float* __restrict__ b_eff,
                       int KD, int C) {
    int i = blockIdx.x * blockDim.x + threadIdx.x;
    if (i < KD) {
        const float* row = conv_w + (size_t)i * C;
        float s = 0.f;
        for (int c = 0; c < C; ++c) s += row[c] * proj_w[c];
        w_eff[i] = s;
    }
    if (i == 0) {
        float s = proj_b[0];
        for (int c = 0; c < C; ++c) s += conv_b[c] * proj_w[c];
        b_eff[0] = s;
    }
}

// K2: alpha[b,t] = sigmoid( dot(eouts[b, t-5 : t+6, :] (flat, 5632 contiguous), w_eff) + b_eff )
// One wave (64 lanes) per (b,t).
__global__ void k_alpha(const float* __restrict__ eouts,
                        const float* __restrict__ w_eff,
                        const float* __restrict__ b_eff,
                        float* __restrict__ alpha,
                        int B, int T, int D) {
    const int W = 2 * KHALF + 1;
    int gid = blockIdx.x * blockDim.x + threadIdx.x;
    int wave = gid >> 6;
    int lane = gid & 63;
    if (wave >= B * T) return;
    int b = wave / T;
    int t = wave - b * T;
    int WD = W * D;
    int t0 = t - KHALF;
    float s = 0.f;
    if (t0 >= 0 && t0 + W <= T) {
        // interior: window is 5632 contiguous floats starting at (b*T + t0)*D
        const float* base = eouts + ((size_t)b * T + t0) * D;
        for (int j = lane * 4; j < WD; j += 256) {
            float4 v = *reinterpret_cast<const float4*>(base + j);
            float4 w = *reinterpret_cast<const float4*>(w_eff + j);
            s += v.x * w.x + v.y * w.y + v.z * w.z + v.w * w.w;
        }
    } else {
        // boundary t (10 per batch): masked scalar path
        const float* base = eouts + (size_t)b * T * D;
        for (int j = lane; j < WD; j += 64) {
            int tt = t0 + j / D;
            if (tt >= 0 && tt < T) {
                int d = j - (j / D) * D;
                s += base[(size_t)tt * D + d] * w_eff[j];
            }
        }
    }
#pragma unroll
    for (int off = 32; off > 0; off >>= 1) s += __shfl_down(s, off, 64);
    if (lane == 0) {
        float logit = s + b_eff[0];
        alpha[(size_t)b * T + t] = 1.f / (1.f + expf(-logit));
    }
}

// K3: per-batch row sum of alpha (for normalization)
__global__ void k_rowsum(const float* __restrict__ alpha, float* __restrict__ alpha_sum, int T) {
    int b = blockIdx.x;
    const float* row = alpha + (size_t)b * T;
    float s = 0.f;
    for (int i = threadIdx.x; i < T; i += blockDim.x) s += row[i];
    __shared__ float sm[16];
    int lane = threadIdx.x & 63;
    int w = threadIdx.x >> 6;
#pragma unroll
    for (int off = 32; off > 0; off >>= 1) s += __shfl_down(s, off, 64);
    if (lane == 0) sm[w] = s;
    __syncthreads();
    if (threadIdx.x == 0) {
        float tot = 0.f;
        int nw = blockDim.x >> 6;
        for (int i = 0; i < nw; ++i) tot += sm[i];
        alpha_sum[b] = tot;
    }
}

// K4: sequential integrate-and-fire scan per batch (scalar chain only).
// Writes aws entries (each element written at most once, background zeroed)
// and records fire times. Block per batch; thread 0 does the scan from LDS.
__global__ void k_scan(const float* __restrict__ alpha,
                       const float* __restrict__ alpha_sum,
                       const int* __restrict__ elens,
                       const int* __restrict__ ylens,
                       float* __restrict__ aws,
                       int* __restrict__ n_fired,
                       int* __restrict__ fire_t,
                       int T, int Lp1) {
    extern __shared__ float an[];
    int b = blockIdx.x;
    float s = alpha_sum[b];
    float yl = (float)ylens[b];
    const float* row = alpha + (size_t)b * T;
    for (int i = threadIdx.x; i < T; i += blockDim.x) an[i] = row[i] / s * yl;
    __syncthreads();
    if (threadIdx.x == 0) {
        int elen = elens[b];
        if (elen > T) elen = T;
        int ylen = ylens[b];
        float accum = 0.f;
        int n = 0;
        float* awb = aws + (size_t)b * Lp1 * T;
        int* ft = fire_t + (size_t)b * Lp1;
        for (int t = 0; t < elen; ++t) {
            float a = an[t];
            accum += a;                    // post-add accumulator (matches ref)
            if (accum >= 0.9f) {           // fire (active guaranteed: t<elen, n<ylen)
                float ak1 = 1.f - accum;
                float ak2 = a - ak1;
                awb[(size_t)n * T + t] = ak1;
                awb[(size_t)(n + 1) * T + t] = ak2;
                ft[n] = t;
                accum = ak2;
                ++n;
                if (n >= ylen) break;      // no further output-affecting work
            } else {
                awb[(size_t)n * T + t] = a;
            }
        }
        n_fired[b] = n;
    }
}

// K5: fired[b,n,:] = sum over token n's window of aws[b,n,t] * eouts[b,t,:]
// Window = [fire_t[n-1], fire_t[n]] inclusive (ak2 carry-in .. ak1 fire step).
// Block (n, b), D threads.
__global__ void k_fired(const float* __restrict__ eouts,
                        const float* __restrict__ aws,
                        const int* __restrict__ n_fired,
                        const int* __restrict__ fire_t,
                        float* __restrict__ fired,
                        int T, int D, int L, int Lp1) {
    int b = blockIdx.y;
    int n = blockIdx.x;
    if (n >= n_fired[b]) return;
    const int* ft = fire_t + (size_t)b * Lp1;
    int t0 = (n == 0) ? 0 : ft[n - 1];
    int t1 = ft[n];
    int d = threadIdx.x;
    const float* aw = aws + ((size_t)b * Lp1 + n) * T;
    const float* e = eouts + ((size_t)b * T + t0) * D + d;
    float acc = 0.f;
    for (int t = t0; t <= t1; ++t, e += D) acc += aw[t] * e[0];
    fired[((size_t)b * L + n) * D + d] = acc;
}

extern "C" void kernel_launch(void* const* d_in, const int* in_sizes, int n_in,
                              void* d_out, int out_size, void* d_ws, size_t ws_size,
                              hipStream_t stream) {
    const float* eouts  = (const float*)d_in[0];
    const float* conv_w = (const float*)d_in[1];
    const float* conv_b = (const float*)d_in[2];
    const float* proj_w = (const float*)d_in[3];
    const float* proj_b = (const float*)d_in[4];
    const int*   elens  = (const int*)d_in[5];
    const int*   ylens  = (const int*)d_in[6];

    const int B = in_sizes[5];
    const int C = in_sizes[2];
    const int W = 2 * KHALF + 1;
    const int D = in_sizes[1] / (W * C);
    const int T = in_sizes[0] / (B * D);
    // out_size = B*L*D + B*T + B*(L+1)*T  =>  L:
    const int L = (out_size - 2 * B * T) / (B * (D + T));
    const int Lp1 = L + 1;

    float* out   = (float*)d_out;
    float* fired = out;                      // [B, L, D]
    float* alpha = out + (size_t)B * L * D;  // [B, T]
    float* aws   = alpha + (size_t)B * T;    // [B, 1, Lp1, T]

    // workspace layout (all written before read within this launch)
    char*  ws        = (char*)d_ws;
    float* w_eff     = (float*)ws;                              // W*D floats
    float* b_eff     = (float*)(ws + (size_t)W * D * 4);        // 1 float (+pad)
    float* alpha_sum = b_eff + 16;                              // B floats
    int*   n_fired   = (int*)(alpha_sum + B + 16);              // B ints
    int*   fire_t    = n_fired + B + 16;                        // B*Lp1 ints

    // zero outputs (fired rows beyond fire count and aws background must be 0)
    hipMemsetAsync(d_out, 0, (size_t)out_size * sizeof(float), stream);

    const int KD = W * D;
    k_weff<<<(KD + 255) / 256, 256, 0, stream>>>(conv_w, conv_b, proj_w, proj_b,
                                                 w_eff, b_eff, KD, C);

    {
        long long threads = (long long)B * T * 64;
        int blocks = (int)((threads + 255) / 256);
        k_alpha<<<blocks, 256, 0, stream>>>(eouts, w_eff, b_eff, alpha, B, T, D);
    }

    k_rowsum<<<B, 256, 0, stream>>>(alpha, alpha_sum, T);

    k_scan<<<B, 256, T * sizeof(float), stream>>>(alpha, alpha_sum, elens, ylens,
                                                  aws, n_fired, fire_t, T, Lp1);

    {
        dim3 g(L, B);
        k_fired<<<g, D, 0, stream>>>(eouts, aws, n_fired, fire_t, fired, T, D, L, Lp1);
    }
}

// Round 2
// 437.453 us; speedup vs baseline: 1.1327x; 1.1327x over previous
//
#include <hip/hip_runtime.h>
#include <math.h>

#define KHALF 5

// K1: effective conv->proj weights: w_eff[k*D+d] = sum_c conv_w[k,d,c]*proj_w[c]
__global__ void k_weff(const float* __restrict__ conv_w, const float* __restrict__ conv_b,
                       const float* __restrict__ proj_w, const float* __restrict__ proj_b,
                       float* __restrict__ w_eff, float* __restrict__ b_eff,
                       int KD, int C) {
    int i = blockIdx.x * blockDim.x + threadIdx.x;
    if (i < KD) {
        const float* row = conv_w + (size_t)i * C;
        float s = 0.f;
        for (int c = 0; c < C; ++c) s += row[c] * proj_w[c];
        w_eff[i] = s;
    }
    if (i == 0) {
        float s = proj_b[0];
        for (int c = 0; c < C; ++c) s += conv_b[c] * proj_w[c];
        b_eff[0] = s;
    }
}

// K2: alpha[b,t] = sigmoid( dot(eouts[b, t-5 : t+6, :] (flat, 5632 contiguous), w_eff) + b_eff )
// One wave (64 lanes) per (b,t).  NOTE: summation order feeds the CIF fire
// threshold downstream — do not change the reduction association.
__global__ void k_alpha(const float* __restrict__ eouts,
                        const float* __restrict__ w_eff,
                        const float* __restrict__ b_eff,
                        float* __restrict__ alpha,
                        int B, int T, int D) {
    const int W = 2 * KHALF + 1;
    int gid = blockIdx.x * blockDim.x + threadIdx.x;
    int wave = gid >> 6;
    int lane = gid & 63;
    if (wave >= B * T) return;
    int b = wave / T;
    int t = wave - b * T;
    int WD = W * D;
    int t0 = t - KHALF;
    float s = 0.f;
    if (t0 >= 0 && t0 + W <= T) {
        // interior: window is 5632 contiguous floats starting at (b*T + t0)*D
        const float* base = eouts + ((size_t)b * T + t0) * D;
        for (int j = lane * 4; j < WD; j += 256) {
            float4 v = *reinterpret_cast<const float4*>(base + j);
            float4 w = *reinterpret_cast<const float4*>(w_eff + j);
            s += v.x * w.x + v.y * w.y + v.z * w.z + v.w * w.w;
        }
    } else {
        // boundary t (10 per batch): masked scalar path
        const float* base = eouts + (size_t)b * T * D;
        for (int j = lane; j < WD; j += 64) {
            int tt = t0 + j / D;
            if (tt >= 0 && tt < T) {
                int d = j - (j / D) * D;
                s += base[(size_t)tt * D + d] * w_eff[j];
            }
        }
    }
#pragma unroll
    for (int off = 32; off > 0; off >>= 1) s += __shfl_down(s, off, 64);
    if (lane == 0) {
        float logit = s + b_eff[0];
        alpha[(size_t)b * T + t] = 1.f / (1.f + expf(-logit));
    }
}

// K3: per-batch row sum of alpha (for normalization)
__global__ void k_rowsum(const float* __restrict__ alpha, float* __restrict__ alpha_sum, int T) {
    int b = blockIdx.x;
    const float* row = alpha + (size_t)b * T;
    float s = 0.f;
    for (int i = threadIdx.x; i < T; i += blockDim.x) s += row[i];
    __shared__ float sm[16];
    int lane = threadIdx.x & 63;
    int w = threadIdx.x >> 6;
#pragma unroll
    for (int off = 32; off > 0; off >>= 1) s += __shfl_down(s, off, 64);
    if (lane == 0) sm[w] = s;
    __syncthreads();
    if (threadIdx.x == 0) {
        float tot = 0.f;
        int nw = blockDim.x >> 6;
        for (int i = 0; i < nw; ++i) tot += sm[i];
        alpha_sum[b] = tot;
    }
}

// K4: sequential integrate-and-fire scan per batch.
// BIT-EXACT fire chain: accum=fl(accum+a); ak1=fl(1-accum); ak2=fl(a-ak1);
// accum=fire?ak2:accum — same op order as the reference scan.
// Restructured for latency: float4 LDS reads (address not data-dependent, so
// the compiler can issue them ahead of the dependent fcmp chain), x4 unroll,
// predicated stores off the critical path.
__global__ void k_scan(const float* __restrict__ alpha,
                       const float* __restrict__ alpha_sum,
                       const int* __restrict__ elens,
                       const int* __restrict__ ylens,
                       float* __restrict__ aws,
                       int* __restrict__ n_fired,
                       int* __restrict__ fire_t,
                       int T, int Lp1) {
    extern __shared__ float an[];
    int b = blockIdx.x;
    float s = alpha_sum[b];
    float yl = (float)ylens[b];
    const float* row = alpha + (size_t)b * T;
    for (int i = threadIdx.x; i < T; i += blockDim.x) an[i] = row[i] / s * yl;
    __syncthreads();
    if (threadIdx.x != 0) return;

    int elen = elens[b];
    if (elen > T) elen = T;
    const int ylen = ylens[b];
    float accum = 0.f;
    int n = 0;
    float* __restrict__ awb = aws + (size_t)b * Lp1 * T;
    int* __restrict__ ft = fire_t + (size_t)b * Lp1;

    int t = 0;
    // main loop: 4 elements per LDS float4 read
    for (; t + 4 <= elen; t += 4) {
        if (n >= ylen) break;  // nothing left that affects outputs
        float4 av = *reinterpret_cast<const float4*>(an + t);
#pragma unroll
        for (int j = 0; j < 4; ++j) {
            float a = (j == 0) ? av.x : (j == 1) ? av.y : (j == 2) ? av.z : av.w;
            accum += a;  // unconditional, matches reference
            if (n < ylen) {
                if (accum >= 0.9f) {
                    float ak1 = 1.f - accum;
                    float ak2 = a - ak1;
                    awb[(size_t)n * T + (t + j)] = ak1;
                    awb[(size_t)(n + 1) * T + (t + j)] = ak2;
                    ft[n] = t + j;
                    accum = ak2;
                    ++n;
                } else {
                    awb[(size_t)n * T + (t + j)] = a;
                }
            }
        }
    }
    // tail
    for (; t < elen && n < ylen; ++t) {
        float a = an[t];
        accum += a;
        if (accum >= 0.9f) {
            float ak1 = 1.f - accum;
            float ak2 = a - ak1;
            awb[(size_t)n * T + t] = ak1;
            awb[(size_t)(n + 1) * T + t] = ak2;
            ft[n] = t;
            accum = ak2;
            ++n;
        } else {
            awb[(size_t)n * T + t] = a;
        }
    }
    n_fired[b] = n;
}

// K5: fired[b,n,:] = sum over token n's window of aws[b,n,t] * eouts[b,t,:]
// Window = [fire_t[n-1], fire_t[n]] inclusive (ak2 carry-in .. ak1 fire step).
// Block (n, b), D threads.
__global__ void k_fired(const float* __restrict__ eouts,
                        const float* __restrict__ aws,
                        const int* __restrict__ n_fired,
                        const int* __restrict__ fire_t,
                        float* __restrict__ fired,
                        int T, int D, int L, int Lp1) {
    int b = blockIdx.y;
    int n = blockIdx.x;
    if (n >= n_fired[b]) return;
    const int* ft = fire_t + (size_t)b * Lp1;
    int t0 = (n == 0) ? 0 : ft[n - 1];
    int t1 = ft[n];
    int d = threadIdx.x;
    const float* aw = aws + ((size_t)b * Lp1 + n) * T;
    const float* e = eouts + ((size_t)b * T + t0) * D + d;
    float acc = 0.f;
    for (int t = t0; t <= t1; ++t, e += D) acc += aw[t] * e[0];
    fired[((size_t)b * L + n) * D + d] = acc;
}

extern "C" void kernel_launch(void* const* d_in, const int* in_sizes, int n_in,
                              void* d_out, int out_size, void* d_ws, size_t ws_size,
                              hipStream_t stream) {
    const float* eouts  = (const float*)d_in[0];
    const float* conv_w = (const float*)d_in[1];
    const float* conv_b = (const float*)d_in[2];
    const float* proj_w = (const float*)d_in[3];
    const float* proj_b = (const float*)d_in[4];
    const int*   elens  = (const int*)d_in[5];
    const int*   ylens  = (const int*)d_in[6];

    const int B = in_sizes[5];
    const int C = in_sizes[2];
    const int W = 2 * KHALF + 1;
    const int D = in_sizes[1] / (W * C);
    const int T = in_sizes[0] / (B * D);
    // out_size = B*L*D + B*T + B*(L+1)*T  =>  L:
    const int L = (out_size - 2 * B * T) / (B * (D + T));
    const int Lp1 = L + 1;

    float* out   = (float*)d_out;
    float* fired = out;                      // [B, L, D]
    float* alpha = out + (size_t)B * L * D;  // [B, T]
    float* aws   = alpha + (size_t)B * T;    // [B, 1, Lp1, T]

    // workspace layout (all written before read within this launch)
    char*  ws        = (char*)d_ws;
    float* w_eff     = (float*)ws;                              // W*D floats
    float* b_eff     = (float*)(ws + (size_t)W * D * 4);        // 1 float (+pad)
    float* alpha_sum = b_eff + 16;                              // B floats
    int*   n_fired   = (int*)(alpha_sum + B + 16);              // B ints
    int*   fire_t    = n_fired + B + 16;                        // B*Lp1 ints

    // zero outputs (fired rows beyond fire count and aws background must be 0)
    hipMemsetAsync(d_out, 0, (size_t)out_size * sizeof(float), stream);

    const int KD = W * D;
    k_weff<<<(KD + 255) / 256, 256, 0, stream>>>(conv_w, conv_b, proj_w, proj_b,
                                                 w_eff, b_eff, KD, C);

    {
        long long threads = (long long)B * T * 64;
        int blocks = (int)((threads + 255) / 256);
        k_alpha<<<blocks, 256, 0, stream>>>(eouts, w_eff, b_eff, alpha, B, T, D);
    }

    k_rowsum<<<B, 256, 0, stream>>>(alpha, alpha_sum, T);

    k_scan<<<B, 256, T * sizeof(float), stream>>>(alpha, alpha_sum, elens, ylens,
                                                  aws, n_fired, fire_t, T, Lp1);

    {
        dim3 g(L, B);
        k_fired<<<g, D, 0, stream>>>(eouts, aws, n_fired, fire_t, fired, T, D, L, Lp1);
    }
}

// Round 3
// 368.352 us; speedup vs baseline: 1.3452x; 1.1876x over previous
//
#include <hip/hip_runtime.h>
#include <math.h>

#define KHALF 5
#define MAXF 256  // max fire count per batch (Lp1 <= 128 for this problem)

// K1: effective conv->proj weights: w_eff[k*D+d] = sum_c conv_w[k,d,c]*proj_w[c]
__global__ void k_weff(const float* __restrict__ conv_w, const float* __restrict__ conv_b,
                       const float* __restrict__ proj_w, const float* __restrict__ proj_b,
                       float* __restrict__ w_eff, float* __restrict__ b_eff,
                       int KD, int C) {
    int i = blockIdx.x * blockDim.x + threadIdx.x;
    if (i < KD) {
        const float* row = conv_w + (size_t)i * C;
        float s = 0.f;
        for (int c = 0; c < C; ++c) s += row[c] * proj_w[c];
        w_eff[i] = s;
    }
    if (i == 0) {
        float s = proj_b[0];
        for (int c = 0; c < C; ++c) s += conv_b[c] * proj_w[c];
        b_eff[0] = s;
    }
}

// K2: alpha[b,t] = sigmoid( dot(eouts[b, t-5 : t+6, :] (flat, 5632 contiguous), w_eff) + b_eff )
// One wave (64 lanes) per (b,t).  NOTE: summation order feeds the CIF fire
// threshold downstream — do not change the reduction association.
__global__ void k_alpha(const float* __restrict__ eouts,
                        const float* __restrict__ w_eff,
                        const float* __restrict__ b_eff,
                        float* __restrict__ alpha,
                        int B, int T, int D) {
    const int W = 2 * KHALF + 1;
    int gid = blockIdx.x * blockDim.x + threadIdx.x;
    int wave = gid >> 6;
    int lane = gid & 63;
    if (wave >= B * T) return;
    int b = wave / T;
    int t = wave - b * T;
    int WD = W * D;
    int t0 = t - KHALF;
    float s = 0.f;
    if (t0 >= 0 && t0 + W <= T) {
        const float* base = eouts + ((size_t)b * T + t0) * D;
        for (int j = lane * 4; j < WD; j += 256) {
            float4 v = *reinterpret_cast<const float4*>(base + j);
            float4 w = *reinterpret_cast<const float4*>(w_eff + j);
            s += v.x * w.x + v.y * w.y + v.z * w.z + v.w * w.w;
        }
    } else {
        const float* base = eouts + (size_t)b * T * D;
        for (int j = lane; j < WD; j += 64) {
            int tt = t0 + j / D;
            if (tt >= 0 && tt < T) {
                int d = j - (j / D) * D;
                s += base[(size_t)tt * D + d] * w_eff[j];
            }
        }
    }
#pragma unroll
    for (int off = 32; off > 0; off >>= 1) s += __shfl_down(s, off, 64);
    if (lane == 0) {
        float logit = s + b_eff[0];
        alpha[(size_t)b * T + t] = 1.f / (1.f + expf(-logit));
    }
}

// K4a: fire-chain only. One block per batch. Row-sum uses the EXACT former
// k_rowsum arithmetic (adds only — no contraction hazard) so `s` is
// bit-identical to round 2. Lane 0 then runs the minimal dependent chain:
// accum=fl(accum+a); cmp>=0.9; on (rare) fire record (t, ak1, ak2), reset.
// No global stores / heavy addressing on the common path.
__global__ void k_chain(const float* __restrict__ alpha,
                        const int* __restrict__ elens,
                        const int* __restrict__ ylens,
                        float* __restrict__ alpha_sum,
                        int* __restrict__ n_fired,
                        int* __restrict__ fire_t,
                        float* __restrict__ fire_a1,
                        float* __restrict__ fire_a2,
                        int T, int Lp1) {
    extern __shared__ float an[];
    __shared__ float sm[16];
    __shared__ float stot;
    int b = blockIdx.x;
    const float* row = alpha + (size_t)b * T;
    // --- row sum (verbatim k_rowsum order) ---
    float s = 0.f;
    for (int i = threadIdx.x; i < T; i += blockDim.x) s += row[i];
    int lane = threadIdx.x & 63;
    int w = threadIdx.x >> 6;
#pragma unroll
    for (int off = 32; off > 0; off >>= 1) s += __shfl_down(s, off, 64);
    if (lane == 0) sm[w] = s;
    __syncthreads();
    if (threadIdx.x == 0) {
        float tot = 0.f;
        int nw = blockDim.x >> 6;
        for (int i = 0; i < nw; ++i) tot += sm[i];
        stot = tot;
        alpha_sum[b] = tot;
    }
    __syncthreads();
    // --- normalize into LDS: an[t] = fl(fl(row[t]/s)*yl) ---
    float ssum = stot;
    float yl = (float)ylens[b];
    for (int i = threadIdx.x; i < T; i += blockDim.x) an[i] = row[i] / ssum * yl;
    __syncthreads();
    if (threadIdx.x != 0) return;

    int elen = elens[b];
    if (elen > T) elen = T;
    const int ylen = ylens[b];
    float accum = 0.f;
    int n = 0;
    int* __restrict__ ft = fire_t + (size_t)b * Lp1;
    float* __restrict__ fa1 = fire_a1 + (size_t)b * Lp1;
    float* __restrict__ fa2 = fire_a2 + (size_t)b * Lp1;

    int t = 0;
    for (; t + 4 <= elen && n < ylen; t += 4) {
        float4 av = *reinterpret_cast<const float4*>(an + t);
#pragma unroll
        for (int j = 0; j < 4; ++j) {
            float a = (j == 0) ? av.x : (j == 1) ? av.y : (j == 2) ? av.z : av.w;
            accum += a;                     // unconditional, matches reference
            if (accum >= 0.9f) {            // rare (~6% of steps)
                if (n < ylen) {
                    float ak1 = 1.f - accum;
                    float ak2 = a - ak1;
                    ft[n] = t + j;
                    fa1[n] = ak1;
                    fa2[n] = ak2;
                    accum = ak2;
                    ++n;
                }
            }
        }
    }
    for (; t < elen && n < ylen; ++t) {
        float a = an[t];
        accum += a;
        if (accum >= 0.9f) {
            float ak1 = 1.f - accum;
            float ak2 = a - ak1;
            ft[n] = t;
            fa1[n] = ak1;
            fa2[n] = ak2;
            accum = ak2;
            ++n;
        }
    }
    n_fired[b] = n;
}

// K4b: parallel aws writer. One thread per (b,t): token row = #fires at times
// < t (binary search in LDS); fire steps write (ak1, ak2) at (row, row+1),
// non-fire active steps write a_t at row. a_t recomputed with the identical
// fl(fl(alpha/s)*yl) sequence as k_chain.
__global__ void k_awrite(const float* __restrict__ alpha,
                         const float* __restrict__ alpha_sum,
                         const int* __restrict__ elens,
                         const int* __restrict__ ylens,
                         const int* __restrict__ n_fired,
                         const int* __restrict__ fire_t,
                         const float* __restrict__ fire_a1,
                         const float* __restrict__ fire_a2,
                         float* __restrict__ aws,
                         int T, int Lp1) {
    __shared__ int fts[MAXF];
    __shared__ float a1s[MAXF];
    __shared__ float a2s[MAXF];
    int b = blockIdx.y;
    int nf = n_fired[b];
    for (int i = threadIdx.x; i < nf; i += blockDim.x) {
        fts[i] = fire_t[(size_t)b * Lp1 + i];
        a1s[i] = fire_a1[(size_t)b * Lp1 + i];
        a2s[i] = fire_a2[(size_t)b * Lp1 + i];
    }
    __syncthreads();
    int t = blockIdx.x * blockDim.x + threadIdx.x;
    if (t >= T) return;
    int elen = elens[b];
    if (elen > T) elen = T;
    if (t >= elen) return;
    int ylen = ylens[b];
    // row = count(ft < t)
    int lo = 0, hi = nf;
    while (lo < hi) {
        int mid = (lo + hi) >> 1;
        if (fts[mid] < t) lo = mid + 1; else hi = mid;
    }
    int rowi = lo;
    float* awb = aws + ((size_t)b * Lp1 + rowi) * T + t;
    if (rowi < nf && fts[rowi] == t) {
        awb[0] = a1s[rowi];
        awb[T] = a2s[rowi];  // row+1, same t
    } else if (rowi < ylen) {
        float a = alpha[(size_t)b * T + t] / alpha_sum[b] * (float)ylen;
        awb[0] = a;
    }
}

// K5: fired[b,n,:] = sum over token n's window of aws[b,n,t] * eouts[b,t,:]
__global__ void k_fired(const float* __restrict__ eouts,
                        const float* __restrict__ aws,
                        const int* __restrict__ n_fired,
                        const int* __restrict__ fire_t,
                        float* __restrict__ fired,
                        int T, int D, int L, int Lp1) {
    int b = blockIdx.y;
    int n = blockIdx.x;
    if (n >= n_fired[b]) return;
    const int* ft = fire_t + (size_t)b * Lp1;
    int t0 = (n == 0) ? 0 : ft[n - 1];
    int t1 = ft[n];
    int d = threadIdx.x;
    const float* aw = aws + ((size_t)b * Lp1 + n) * T;
    const float* e = eouts + ((size_t)b * T + t0) * D + d;
    float acc = 0.f;
    for (int t = t0; t <= t1; ++t, e += D) acc += aw[t] * e[0];
    fired[((size_t)b * L + n) * D + d] = acc;
}

extern "C" void kernel_launch(void* const* d_in, const int* in_sizes, int n_in,
                              void* d_out, int out_size, void* d_ws, size_t ws_size,
                              hipStream_t stream) {
    const float* eouts  = (const float*)d_in[0];
    const float* conv_w = (const float*)d_in[1];
    const float* conv_b = (const float*)d_in[2];
    const float* proj_w = (const float*)d_in[3];
    const float* proj_b = (const float*)d_in[4];
    const int*   elens  = (const int*)d_in[5];
    const int*   ylens  = (const int*)d_in[6];

    const int B = in_sizes[5];
    const int C = in_sizes[2];
    const int W = 2 * KHALF + 1;
    const int D = in_sizes[1] / (W * C);
    const int T = in_sizes[0] / (B * D);
    const int L = (out_size - 2 * B * T) / (B * (D + T));
    const int Lp1 = L + 1;

    float* out   = (float*)d_out;
    float* fired = out;                      // [B, L, D]
    float* alpha = out + (size_t)B * L * D;  // [B, T]
    float* aws   = alpha + (size_t)B * T;    // [B, 1, Lp1, T]

    // workspace layout (all written before read within this launch)
    char*  ws        = (char*)d_ws;
    float* w_eff     = (float*)ws;                              // W*D floats
    float* b_eff     = (float*)(ws + (size_t)W * D * 4);        // 1 float (+pad)
    float* alpha_sum = b_eff + 16;                              // B floats
    int*   n_fired   = (int*)(alpha_sum + B + 16);              // B ints
    int*   fire_t    = n_fired + B + 16;                        // B*Lp1 ints
    float* fire_a1   = (float*)(fire_t + (size_t)B * Lp1 + 16); // B*Lp1 floats
    float* fire_a2   = fire_a1 + (size_t)B * Lp1 + 16;          // B*Lp1 floats

    // zero outputs (fired rows beyond fire count and aws background must be 0)
    hipMemsetAsync(d_out, 0, (size_t)out_size * sizeof(float), stream);

    const int KD = W * D;
    k_weff<<<(KD + 255) / 256, 256, 0, stream>>>(conv_w, conv_b, proj_w, proj_b,
                                                 w_eff, b_eff, KD, C);

    {
        long long threads = (long long)B * T * 64;
        int blocks = (int)((threads + 255) / 256);
        k_alpha<<<blocks, 256, 0, stream>>>(eouts, w_eff, b_eff, alpha, B, T, D);
    }

    k_chain<<<B, 256, T * sizeof(float), stream>>>(alpha, elens, ylens, alpha_sum,
                                                   n_fired, fire_t, fire_a1, fire_a2,
                                                   T, Lp1);

    {
        dim3 g((T + 255) / 256, B);
        k_awrite<<<g, 256, 0, stream>>>(alpha, alpha_sum, elens, ylens,
                                        n_fired, fire_t, fire_a1, fire_a2,
                                        aws, T, Lp1);
    }

    {
        dim3 g(L, B);
        k_fired<<<g, D, 0, stream>>>(eouts, aws, n_fired, fire_t, fired, T, D, L, Lp1);
    }
}

// Round 4
// 232.930 us; speedup vs baseline: 2.1272x; 1.5814x over previous
//
#include <hip/hip_runtime.h>
#include <math.h>

#define KHALF 5
#define MAXF 256  // max fire count per batch (Lp1 <= 128 for this problem)

// K1: effective conv->proj weights: w_eff[k*D+d] = sum_c conv_w[k,d,c]*proj_w[c]
// One WAVE per output element; lanes stride C with float4 (coalesced), shuffle
// reduce. Extra wave (wave==KD) computes b_eff.
__global__ void k_weff(const float* __restrict__ conv_w, const float* __restrict__ conv_b,
                       const float* __restrict__ proj_w, const float* __restrict__ proj_b,
                       float* __restrict__ w_eff, float* __restrict__ b_eff,
                       int KD, int C) {
    int gid = blockIdx.x * blockDim.x + threadIdx.x;
    int wave = gid >> 6;
    int lane = gid & 63;
    if (wave > KD) return;
    float s = 0.f;
    if (wave < KD) {
        const float* row = conv_w + (size_t)wave * C;
        for (int c = lane * 4; c < C; c += 256) {
            float4 v = *reinterpret_cast<const float4*>(row + c);
            float4 w = *reinterpret_cast<const float4*>(proj_w + c);
            s += v.x * w.x + v.y * w.y + v.z * w.z + v.w * w.w;
        }
    } else {
        for (int c = lane; c < C; c += 64) s += conv_b[c] * proj_w[c];
    }
#pragma unroll
    for (int off = 32; off > 0; off >>= 1) s += __shfl_down(s, off, 64);
    if (lane == 0) {
        if (wave < KD) w_eff[wave] = s;
        else           b_eff[0] = s + proj_b[0];
    }
}

// K2: alpha[b,t] = sigmoid( dot(eouts[b, t-5 : t+6, :] (flat, 5632 contiguous), w_eff) + b_eff )
// One wave (64 lanes) per (b,t).
__global__ void k_alpha(const float* __restrict__ eouts,
                        const float* __restrict__ w_eff,
                        const float* __restrict__ b_eff,
                        float* __restrict__ alpha,
                        int B, int T, int D) {
    const int W = 2 * KHALF + 1;
    int gid = blockIdx.x * blockDim.x + threadIdx.x;
    int wave = gid >> 6;
    int lane = gid & 63;
    if (wave >= B * T) return;
    int b = wave / T;
    int t = wave - b * T;
    int WD = W * D;
    int t0 = t - KHALF;
    float s = 0.f;
    if (t0 >= 0 && t0 + W <= T) {
        const float* base = eouts + ((size_t)b * T + t0) * D;
        for (int j = lane * 4; j < WD; j += 256) {
            float4 v = *reinterpret_cast<const float4*>(base + j);
            float4 w = *reinterpret_cast<const float4*>(w_eff + j);
            s += v.x * w.x + v.y * w.y + v.z * w.z + v.w * w.w;
        }
    } else {
        const float* base = eouts + (size_t)b * T * D;
        for (int j = lane; j < WD; j += 64) {
            int tt = t0 + j / D;
            if (tt >= 0 && tt < T) {
                int d = j - (j / D) * D;
                s += base[(size_t)tt * D + d] * w_eff[j];
            }
        }
    }
#pragma unroll
    for (int off = 32; off > 0; off >>= 1) s += __shfl_down(s, off, 64);
    if (lane == 0) {
        float logit = s + b_eff[0];
        alpha[(size_t)b * T + t] = 1.f / (1.f + expf(-logit));
    }
}

// K4a: fire chain, wave-parallel segmented threshold scan.
// Block per batch: 256 threads do row-sum + normalize into LDS, then wave 0
// scans in 64-element chunks: inclusive prefix sum (shfl_up), fires located
// by ballot(base+P >= 0.9); per fire, base' = ak2 - P(u), re-ballot from u+1.
// Reassociates the accumulator by ~ulps (flip risk analyzed: ~0.3%/version).
__global__ void k_chain(const float* __restrict__ alpha,
                        const int* __restrict__ elens,
                        const int* __restrict__ ylens,
                        float* __restrict__ alpha_sum,
                        int* __restrict__ n_fired,
                        int* __restrict__ fire_t,
                        float* __restrict__ fire_a1,
                        float* __restrict__ fire_a2,
                        int T, int Lp1) {
    extern __shared__ float an[];
    __shared__ float sm[16];
    __shared__ float stot;
    int b = blockIdx.x;
    const float* row = alpha + (size_t)b * T;
    // --- row sum ---
    float s = 0.f;
    for (int i = threadIdx.x; i < T; i += blockDim.x) s += row[i];
    int lane = threadIdx.x & 63;
    int w = threadIdx.x >> 6;
#pragma unroll
    for (int off = 32; off > 0; off >>= 1) s += __shfl_down(s, off, 64);
    if (lane == 0) sm[w] = s;
    __syncthreads();
    if (threadIdx.x == 0) {
        float tot = 0.f;
        int nw = blockDim.x >> 6;
        for (int i = 0; i < nw; ++i) tot += sm[i];
        stot = tot;
        alpha_sum[b] = tot;
    }
    __syncthreads();
    // --- normalize into LDS: an[t] = fl(fl(row[t]/s)*yl) ---
    float ssum = stot;
    float yl = (float)ylens[b];
    for (int i = threadIdx.x; i < T; i += blockDim.x) an[i] = row[i] / ssum * yl;
    __syncthreads();
    if (threadIdx.x >= 64) return;  // wave 0 only from here

    int elen = elens[b];
    if (elen > T) elen = T;
    const int ylen = ylens[b];
    int* __restrict__ ft = fire_t + (size_t)b * Lp1;
    float* __restrict__ fa1 = fire_a1 + (size_t)b * Lp1;
    float* __restrict__ fa2 = fire_a2 + (size_t)b * Lp1;

    float accum = 0.f;
    int n = 0;
    bool done = false;
    for (int t0 = 0; t0 < elen && !done; t0 += 64) {
        int nv = elen - t0;
        if (nv > 64) nv = 64;
        float a = (lane < nv) ? an[t0 + lane] : 0.f;
        // inclusive prefix sum across the wave
        float P = a;
#pragma unroll
        for (int off = 1; off < 64; off <<= 1) {
            float tmp = __shfl_up(P, off, 64);
            if (lane >= off) P += tmp;
        }
        unsigned long long validmask =
            (nv == 64) ? ~0ull : ((1ull << nv) - 1ull);
        float base = accum;
        int start = 0;
        while (true) {
            bool cond = (base + P >= 0.9f);
            unsigned long long bal = __ballot(cond) & validmask;
            if (start > 0) bal &= (~0ull) << start;  // lanes >= start
            if (bal == 0) break;
            int u = __builtin_ctzll(bal);
            float Pu = __shfl(P, u, 64);
            float au = __shfl(a, u, 64);
            float accum_f = base + Pu;
            float ak1 = 1.f - accum_f;
            float ak2 = au - ak1;
            if (lane == 0) {
                ft[n] = t0 + u;
                fa1[n] = ak1;
                fa2[n] = ak2;
            }
            ++n;
            if (n >= ylen) { done = true; break; }
            base = ak2 - Pu;
            start = u + 1;
            if (start >= nv) break;
        }
        if (!done) {
            float Plast = __shfl(P, nv - 1, 64);
            accum = base + Plast;
        }
    }
    if (lane == 0) n_fired[b] = n;
}

// K4b: parallel aws writer. One thread per (b,t): token row = #fires at times
// < t (binary search in LDS); fire steps write (ak1, ak2) at (row, row+1),
// non-fire active steps write a_t at row. a_t recomputed with the identical
// fl(fl(alpha/s)*yl) sequence as k_chain.
__global__ void k_awrite(const float* __restrict__ alpha,
                         const float* __restrict__ alpha_sum,
                         const int* __restrict__ elens,
                         const int* __restrict__ ylens,
                         const int* __restrict__ n_fired,
                         const int* __restrict__ fire_t,
                         const float* __restrict__ fire_a1,
                         const float* __restrict__ fire_a2,
                         float* __restrict__ aws,
                         int T, int Lp1) {
    __shared__ int fts[MAXF];
    __shared__ float a1s[MAXF];
    __shared__ float a2s[MAXF];
    int b = blockIdx.y;
    int nf = n_fired[b];
    for (int i = threadIdx.x; i < nf; i += blockDim.x) {
        fts[i] = fire_t[(size_t)b * Lp1 + i];
        a1s[i] = fire_a1[(size_t)b * Lp1 + i];
        a2s[i] = fire_a2[(size_t)b * Lp1 + i];
    }
    __syncthreads();
    int t = blockIdx.x * blockDim.x + threadIdx.x;
    if (t >= T) return;
    int elen = elens[b];
    if (elen > T) elen = T;
    if (t >= elen) return;
    int ylen = ylens[b];
    // row = count(ft < t)
    int lo = 0, hi = nf;
    while (lo < hi) {
        int mid = (lo + hi) >> 1;
        if (fts[mid] < t) lo = mid + 1; else hi = mid;
    }
    int rowi = lo;
    float* awb = aws + ((size_t)b * Lp1 + rowi) * T + t;
    if (rowi < nf && fts[rowi] == t) {
        awb[0] = a1s[rowi];
        awb[T] = a2s[rowi];  // row+1, same t
    } else if (rowi < ylen) {
        float a = alpha[(size_t)b * T + t] / alpha_sum[b] * (float)ylen;
        awb[0] = a;
    }
}

// K5: fired[b,n,:] = sum over token n's window of aws[b,n,t] * eouts[b,t,:]
__global__ void k_fired(const float* __restrict__ eouts,
                        const float* __restrict__ aws,
                        const int* __restrict__ n_fired,
                        const int* __restrict__ fire_t,
                        float* __restrict__ fired,
                        int T, int D, int L, int Lp1) {
    int b = blockIdx.y;
    int n = blockIdx.x;
    if (n >= n_fired[b]) return;
    const int* ft = fire_t + (size_t)b * Lp1;
    int t0 = (n == 0) ? 0 : ft[n - 1];
    int t1 = ft[n];
    int d = threadIdx.x;
    const float* aw = aws + ((size_t)b * Lp1 + n) * T;
    const float* e = eouts + ((size_t)b * T + t0) * D + d;
    float acc = 0.f;
    for (int t = t0; t <= t1; ++t, e += D) acc += aw[t] * e[0];
    fired[((size_t)b * L + n) * D + d] = acc;
}

extern "C" void kernel_launch(void* const* d_in, const int* in_sizes, int n_in,
                              void* d_out, int out_size, void* d_ws, size_t ws_size,
                              hipStream_t stream) {
    const float* eouts  = (const float*)d_in[0];
    const float* conv_w = (const float*)d_in[1];
    const float* conv_b = (const float*)d_in[2];
    const float* proj_w = (const float*)d_in[3];
    const float* proj_b = (const float*)d_in[4];
    const int*   elens  = (const int*)d_in[5];
    const int*   ylens  = (const int*)d_in[6];

    const int B = in_sizes[5];
    const int C = in_sizes[2];
    const int W = 2 * KHALF + 1;
    const int D = in_sizes[1] / (W * C);
    const int T = in_sizes[0] / (B * D);
    const int L = (out_size - 2 * B * T) / (B * (D + T));
    const int Lp1 = L + 1;

    float* out   = (float*)d_out;
    float* fired = out;                      // [B, L, D]
    float* alpha = out + (size_t)B * L * D;  // [B, T]
    float* aws   = alpha + (size_t)B * T;    // [B, 1, Lp1, T]

    // workspace layout (all written before read within this launch)
    char*  ws        = (char*)d_ws;
    float* w_eff     = (float*)ws;                              // W*D floats
    float* b_eff     = (float*)(ws + (size_t)W * D * 4);        // 1 float (+pad)
    float* alpha_sum = b_eff + 16;                              // B floats
    int*   n_fired   = (int*)(alpha_sum + B + 16);              // B ints
    int*   fire_t    = n_fired + B + 16;                        // B*Lp1 ints
    float* fire_a1   = (float*)(fire_t + (size_t)B * Lp1 + 16); // B*Lp1 floats
    float* fire_a2   = fire_a1 + (size_t)B * Lp1 + 16;          // B*Lp1 floats

    // zero outputs (fired rows beyond fire count and aws background must be 0)
    hipMemsetAsync(d_out, 0, (size_t)out_size * sizeof(float), stream);

    const int KD = W * D;
    {
        // one wave per output + 1 wave for b_eff
        long long threads = (long long)(KD + 1) * 64;
        int blocks = (int)((threads + 255) / 256);
        k_weff<<<blocks, 256, 0, stream>>>(conv_w, conv_b, proj_w, proj_b,
                                           w_eff, b_eff, KD, C);
    }

    {
        long long threads = (long long)B * T * 64;
        int blocks = (int)((threads + 255) / 256);
        k_alpha<<<blocks, 256, 0, stream>>>(eouts, w_eff, b_eff, alpha, B, T, D);
    }

    k_chain<<<B, 256, T * sizeof(float), stream>>>(alpha, elens, ylens, alpha_sum,
                                                   n_fired, fire_t, fire_a1, fire_a2,
                                                   T, Lp1);

    {
        dim3 g((T + 255) / 256, B);
        k_awrite<<<g, 256, 0, stream>>>(alpha, alpha_sum, elens, ylens,
                                        n_fired, fire_t, fire_a1, fire_a2,
                                        aws, T, Lp1);
    }

    {
        dim3 g(L, B);
        k_fired<<<g, D, 0, stream>>>(eouts, aws, n_fired, fire_t, fired, T, D, L, Lp1);
    }
}

// Round 5
// 207.395 us; speedup vs baseline: 2.3891x; 1.1231x over previous
//
#include <hip/hip_runtime.h>
#include <math.h>

#define KHALF 5
#define MAXF 256  // max fire count per batch (Lp1 <= 128 for this problem)

// K1: effective conv->proj weights: w_eff[k*D+d] = sum_c conv_w[k,d,c]*proj_w[c]
// One WAVE per output element; lanes stride C with float4 (coalesced), shuffle
// reduce. Extra wave (wave==KD) computes b_eff.
__global__ void k_weff(const float* __restrict__ conv_w, const float* __restrict__ conv_b,
                       const float* __restrict__ proj_w, const float* __restrict__ proj_b,
                       float* __restrict__ w_eff, float* __restrict__ b_eff,
                       int KD, int C) {
    int gid = blockIdx.x * blockDim.x + threadIdx.x;
    int wave = gid >> 6;
    int lane = gid & 63;
    if (wave > KD) return;
    float s = 0.f;
    if (wave < KD) {
        const float* row = conv_w + (size_t)wave * C;
        for (int c = lane * 4; c < C; c += 256) {
            float4 v = *reinterpret_cast<const float4*>(row + c);
            float4 w = *reinterpret_cast<const float4*>(proj_w + c);
            s += v.x * w.x + v.y * w.y + v.z * w.z + v.w * w.w;
        }
    } else {
        for (int c = lane; c < C; c += 64) s += conv_b[c] * proj_w[c];
    }
#pragma unroll
    for (int off = 32; off > 0; off >>= 1) s += __shfl_down(s, off, 64);
    if (lane == 0) {
        if (wave < KD) w_eff[wave] = s;
        else           b_eff[0] = s + proj_b[0];
    }
}

// K2a: q[u][k] = dot(eouts[u,:], w_eff[k,:]) for k=0..10.
// One wave per row u (u = b*T+t, rows contiguous). Each eouts element read
// from HBM exactly ONCE (vs 11x in the windowed formulation). Lane l owns
// d in {4l..4l+3} u {256+4l..256+4l+3}: coalesced global float4; LDS w_eff
// reads at 2-way bank aliasing (free). Butterfly all-reduce per k.
__global__ void k_qdot(const float* __restrict__ eouts,
                       const float* __restrict__ w_eff,
                       float* __restrict__ q,
                       int BT, int D, int WD) {
    __shared__ float wsh[5632];
    for (int i = threadIdx.x; i < WD; i += blockDim.x) wsh[i] = w_eff[i];
    __syncthreads();
    int gid = blockIdx.x * blockDim.x + threadIdx.x;
    int u = gid >> 6;
    int lane = gid & 63;
    if (u >= BT) return;
    const float* row = eouts + (size_t)u * D;
    float4 e0 = *reinterpret_cast<const float4*>(row + lane * 4);
    float4 e1 = *reinterpret_cast<const float4*>(row + 256 + lane * 4);
    float myq = 0.f;
#pragma unroll
    for (int k = 0; k < 11; ++k) {
        const float* wp = wsh + k * 512;
        float4 w0 = *reinterpret_cast<const float4*>(wp + lane * 4);
        float4 w1 = *reinterpret_cast<const float4*>(wp + 256 + lane * 4);
        float s = e0.x * w0.x + e0.y * w0.y + e0.z * w0.z + e0.w * w0.w
                + e1.x * w1.x + e1.y * w1.y + e1.z * w1.z + e1.w * w1.w;
#pragma unroll
        for (int off = 32; off > 0; off >>= 1) s += __shfl_xor(s, off, 64);
        if (lane == k) myq = s;
    }
    if (lane < 11) q[(size_t)u * 12 + lane] = myq;
}

// K2b: alpha[b,t] = sigmoid( sum_k q[t-5+k][k] + b_eff ), zero-padded window.
__global__ void k_sigma(const float* __restrict__ q,
                        const float* __restrict__ b_eff,
                        float* __restrict__ alpha,
                        int B, int T) {
    int i = blockIdx.x * blockDim.x + threadIdx.x;
    if (i >= B * T) return;
    int t = i % T;
    int rowbase = i - t;
    float s = b_eff[0];
    int t0 = t - KHALF;
#pragma unroll
    for (int k = 0; k < 11; ++k) {
        int u = t0 + k;
        if (u >= 0 && u < T) s += q[(size_t)(rowbase + u) * 12 + k];
    }
    alpha[i] = 1.f / (1.f + expf(-s));
}

// K2 (fallback if ws too small for q): original windowed dot, one wave per (b,t).
__global__ void k_alpha(const float* __restrict__ eouts,
                        const float* __restrict__ w_eff,
                        const float* __restrict__ b_eff,
                        float* __restrict__ alpha,
                        int B, int T, int D) {
    const int W = 2 * KHALF + 1;
    int gid = blockIdx.x * blockDim.x + threadIdx.x;
    int wave = gid >> 6;
    int lane = gid & 63;
    if (wave >= B * T) return;
    int b = wave / T;
    int t = wave - b * T;
    int WD = W * D;
    int t0 = t - KHALF;
    float s = 0.f;
    if (t0 >= 0 && t0 + W <= T) {
        const float* base = eouts + ((size_t)b * T + t0) * D;
        for (int j = lane * 4; j < WD; j += 256) {
            float4 v = *reinterpret_cast<const float4*>(base + j);
            float4 w = *reinterpret_cast<const float4*>(w_eff + j);
            s += v.x * w.x + v.y * w.y + v.z * w.z + v.w * w.w;
        }
    } else {
        const float* base = eouts + (size_t)b * T * D;
        for (int j = lane; j < WD; j += 64) {
            int tt = t0 + j / D;
            if (tt >= 0 && tt < T) {
                int d = j - (j / D) * D;
                s += base[(size_t)tt * D + d] * w_eff[j];
            }
        }
    }
#pragma unroll
    for (int off = 32; off > 0; off >>= 1) s += __shfl_down(s, off, 64);
    if (lane == 0) {
        float logit = s + b_eff[0];
        alpha[(size_t)b * T + t] = 1.f / (1.f + expf(-logit));
    }
}

// K4a: fire chain, wave-parallel segmented threshold scan.
__global__ void k_chain(const float* __restrict__ alpha,
                        const int* __restrict__ elens,
                        const int* __restrict__ ylens,
                        float* __restrict__ alpha_sum,
                        int* __restrict__ n_fired,
                        int* __restrict__ fire_t,
                        float* __restrict__ fire_a1,
                        float* __restrict__ fire_a2,
                        int T, int Lp1) {
    extern __shared__ float an[];
    __shared__ float sm[16];
    __shared__ float stot;
    int b = blockIdx.x;
    const float* row = alpha + (size_t)b * T;
    // --- row sum ---
    float s = 0.f;
    for (int i = threadIdx.x; i < T; i += blockDim.x) s += row[i];
    int lane = threadIdx.x & 63;
    int w = threadIdx.x >> 6;
#pragma unroll
    for (int off = 32; off > 0; off >>= 1) s += __shfl_down(s, off, 64);
    if (lane == 0) sm[w] = s;
    __syncthreads();
    if (threadIdx.x == 0) {
        float tot = 0.f;
        int nw = blockDim.x >> 6;
        for (int i = 0; i < nw; ++i) tot += sm[i];
        stot = tot;
        alpha_sum[b] = tot;
    }
    __syncthreads();
    float ssum = stot;
    float yl = (float)ylens[b];
    for (int i = threadIdx.x; i < T; i += blockDim.x) an[i] = row[i] / ssum * yl;
    __syncthreads();
    if (threadIdx.x >= 64) return;  // wave 0 only from here

    int elen = elens[b];
    if (elen > T) elen = T;
    const int ylen = ylens[b];
    int* __restrict__ ft = fire_t + (size_t)b * Lp1;
    float* __restrict__ fa1 = fire_a1 + (size_t)b * Lp1;
    float* __restrict__ fa2 = fire_a2 + (size_t)b * Lp1;

    float accum = 0.f;
    int n = 0;
    bool done = false;
    for (int t0 = 0; t0 < elen && !done; t0 += 64) {
        int nv = elen - t0;
        if (nv > 64) nv = 64;
        float a = (lane < nv) ? an[t0 + lane] : 0.f;
        float P = a;
#pragma unroll
        for (int off = 1; off < 64; off <<= 1) {
            float tmp = __shfl_up(P, off, 64);
            if (lane >= off) P += tmp;
        }
        unsigned long long validmask =
            (nv == 64) ? ~0ull : ((1ull << nv) - 1ull);
        float base = accum;
        int start = 0;
        while (true) {
            bool cond = (base + P >= 0.9f);
            unsigned long long bal = __ballot(cond) & validmask;
            if (start > 0) bal &= (~0ull) << start;
            if (bal == 0) break;
            int u = __builtin_ctzll(bal);
            float Pu = __shfl(P, u, 64);
            float au = __shfl(a, u, 64);
            float accum_f = base + Pu;
            float ak1 = 1.f - accum_f;
            float ak2 = au - ak1;
            if (lane == 0) {
                ft[n] = t0 + u;
                fa1[n] = ak1;
                fa2[n] = ak2;
            }
            ++n;
            if (n >= ylen) { done = true; break; }
            base = ak2 - Pu;
            start = u + 1;
            if (start >= nv) break;
        }
        if (!done) {
            float Plast = __shfl(P, nv - 1, 64);
            accum = base + Plast;
        }
    }
    if (lane == 0) n_fired[b] = n;
}

// K4b: parallel aws writer (binary search over fire times).
__global__ void k_awrite(const float* __restrict__ alpha,
                         const float* __restrict__ alpha_sum,
                         const int* __restrict__ elens,
                         const int* __restrict__ ylens,
                         const int* __restrict__ n_fired,
                         const int* __restrict__ fire_t,
                         const float* __restrict__ fire_a1,
                         const float* __restrict__ fire_a2,
                         float* __restrict__ aws,
                         int T, int Lp1) {
    __shared__ int fts[MAXF];
    __shared__ float a1s[MAXF];
    __shared__ float a2s[MAXF];
    int b = blockIdx.y;
    int nf = n_fired[b];
    for (int i = threadIdx.x; i < nf; i += blockDim.x) {
        fts[i] = fire_t[(size_t)b * Lp1 + i];
        a1s[i] = fire_a1[(size_t)b * Lp1 + i];
        a2s[i] = fire_a2[(size_t)b * Lp1 + i];
    }
    __syncthreads();
    int t = blockIdx.x * blockDim.x + threadIdx.x;
    if (t >= T) return;
    int elen = elens[b];
    if (elen > T) elen = T;
    if (t >= elen) return;
    int ylen = ylens[b];
    int lo = 0, hi = nf;
    while (lo < hi) {
        int mid = (lo + hi) >> 1;
        if (fts[mid] < t) lo = mid + 1; else hi = mid;
    }
    int rowi = lo;
    float* awb = aws + ((size_t)b * Lp1 + rowi) * T + t;
    if (rowi < nf && fts[rowi] == t) {
        awb[0] = a1s[rowi];
        awb[T] = a2s[rowi];
    } else if (rowi < ylen) {
        float a = alpha[(size_t)b * T + t] / alpha_sum[b] * (float)ylen;
        awb[0] = a;
    }
}

// K5: fired[b,n,:] = sum over token n's window of aws[b,n,t] * eouts[b,t,:]
__global__ void k_fired(const float* __restrict__ eouts,
                        const float* __restrict__ aws,
                        const int* __restrict__ n_fired,
                        const int* __restrict__ fire_t,
                        float* __restrict__ fired,
                        int T, int D, int L, int Lp1) {
    int b = blockIdx.y;
    int n = blockIdx.x;
    if (n >= n_fired[b]) return;
    const int* ft = fire_t + (size_t)b * Lp1;
    int t0 = (n == 0) ? 0 : ft[n - 1];
    int t1 = ft[n];
    int d = threadIdx.x;
    const float* aw = aws + ((size_t)b * Lp1 + n) * T;
    const float* e = eouts + ((size_t)b * T + t0) * D + d;
    float acc = 0.f;
    for (int t = t0; t <= t1; ++t, e += D) acc += aw[t] * e[0];
    fired[((size_t)b * L + n) * D + d] = acc;
}

extern "C" void kernel_launch(void* const* d_in, const int* in_sizes, int n_in,
                              void* d_out, int out_size, void* d_ws, size_t ws_size,
                              hipStream_t stream) {
    const float* eouts  = (const float*)d_in[0];
    const float* conv_w = (const float*)d_in[1];
    const float* conv_b = (const float*)d_in[2];
    const float* proj_w = (const float*)d_in[3];
    const float* proj_b = (const float*)d_in[4];
    const int*   elens  = (const int*)d_in[5];
    const int*   ylens  = (const int*)d_in[6];

    const int B = in_sizes[5];
    const int C = in_sizes[2];
    const int W = 2 * KHALF + 1;
    const int D = in_sizes[1] / (W * C);
    const int T = in_sizes[0] / (B * D);
    const int L = (out_size - 2 * B * T) / (B * (D + T));
    const int Lp1 = L + 1;
    const int BT = B * T;

    float* out   = (float*)d_out;
    float* fired = out;                      // [B, L, D]
    float* alpha = out + (size_t)B * L * D;  // [B, T]
    float* aws   = alpha + (size_t)B * T;    // [B, 1, Lp1, T]

    // workspace layout (all written before read within this launch)
    char*  ws        = (char*)d_ws;
    float* w_eff     = (float*)ws;                              // W*D floats
    float* b_eff     = (float*)(ws + (size_t)W * D * 4);        // 1 float (+pad)
    float* alpha_sum = b_eff + 16;                              // B floats
    int*   n_fired   = (int*)(alpha_sum + B + 16);              // B ints
    int*   fire_t    = n_fired + B + 16;                        // B*Lp1 ints
    float* fire_a1   = (float*)(fire_t + (size_t)B * Lp1 + 16); // B*Lp1 floats
    float* fire_a2   = fire_a1 + (size_t)B * Lp1 + 16;          // B*Lp1 floats
    float* qbuf      = fire_a2 + (size_t)B * Lp1 + 16;          // BT*12 floats
    size_t ws_need   = (size_t)((char*)(qbuf + (size_t)BT * 12) - ws);

    // zero outputs (fired rows beyond fire count and aws background must be 0)
    hipMemsetAsync(d_out, 0, (size_t)out_size * sizeof(float), stream);

    const int KD = W * D;
    {
        long long threads = (long long)(KD + 1) * 64;
        int blocks = (int)((threads + 255) / 256);
        k_weff<<<blocks, 256, 0, stream>>>(conv_w, conv_b, proj_w, proj_b,
                                           w_eff, b_eff, KD, C);
    }

    if (ws_size >= ws_need && D == 512) {
        // read-once k-decomposition: q[u][k] then diagonal sum + sigmoid
        long long threads = (long long)BT * 64;
        int blocks = (int)((threads + 255) / 256);
        k_qdot<<<blocks, 256, 0, stream>>>(eouts, w_eff, qbuf, BT, D, KD);
        k_sigma<<<(BT + 255) / 256, 256, 0, stream>>>(qbuf, b_eff, alpha, B, T);
    } else {
        long long threads = (long long)BT * 64;
        int blocks = (int)((threads + 255) / 256);
        k_alpha<<<blocks, 256, 0, stream>>>(eouts, w_eff, b_eff, alpha, B, T, D);
    }

    k_chain<<<B, 256, T * sizeof(float), stream>>>(alpha, elens, ylens, alpha_sum,
                                                   n_fired, fire_t, fire_a1, fire_a2,
                                                   T, Lp1);

    {
        dim3 g((T + 255) / 256, B);
        k_awrite<<<g, 256, 0, stream>>>(alpha, alpha_sum, elens, ylens,
                                        n_fired, fire_t, fire_a1, fire_a2,
                                        aws, T, Lp1);
    }

    {
        dim3 g(L, B);
        k_fired<<<g, D, 0, stream>>>(eouts, aws, n_fired, fire_t, fired, T, D, L, Lp1);
    }
}